// Round 4
// baseline (48.606 us; speedup 1.0000x reference)
//
#include <hip/hip_runtime.h>

#define HWD    48400          // 220*220
#define PATCHD 75
#define DWPC   84             // dwords per [col] row of B in LDS (80 data + 4 pad) -> 336B stride

typedef __attribute__((ext_vector_type(8))) _Float16 f16x8;
typedef __attribute__((ext_vector_type(2))) __fp16   h16x2;   // cvt_pkrtz return type
typedef __attribute__((ext_vector_type(4))) float    f32x4;

union U2 { h16x2 h; unsigned u; };
union UA { unsigned u[4]; f16x8 v; };

// kappa layout (K = 160, 5 MFMA K-steps of 32):
//   kappa in [0,75)    : A = E*x (dir1) / -R*x (dir2);  B(num col) = a = exp(w); B(den col) = 0
//   kappa in [75,80)   : zero pad
//   kappa in [80,155)  : A = E (dir1) / R (dir2);       B(num col) = w*exp(w);  B(den col) = exp(w)
//   kappa in [155,160) : zero pad
// num[c] = sum Ex*a + E*b ; den[c] = sum E*a  (dir2 analogous with R, -Rx)

__global__ __launch_bounds__(256)
void smorph_mfma(const float* __restrict__ x,
                 const float* __restrict__ k1,
                 const float* __restrict__ k2,
                 const float* __restrict__ bias,
                 float* __restrict__ out)
{
    // B tables: [dir][col(32)][kappa as 80 dwords of f16x2 (+4 pad)]
    __shared__ __align__(16) unsigned sB[2 * 32 * DWPC];

    const int tid = (int)threadIdx.x;

    // ---- cooperative B build: 5120 dwords, 20 per thread ----
    for (int d = tid; d < 2 * 32 * 80; d += 256) {
        const int dir = d / 2560;
        const int r   = d - dir * 2560;
        const int col = r / 80;
        const int kd  = r - col * 80;
        const float* kw = dir ? k2 : k1;
        float v[2];
        #pragma unroll
        for (int h = 0; h < 2; ++h) {
            const int kap = kd * 2 + h;
            float val = 0.f;
            if (col < 16) {                       // num columns, channel = col
                if (kap < 75) {
                    val = __expf(kw[kap * 16 + col]);                 // a
                } else if (kap >= 80 && kap < 155) {
                    const float w = kw[(kap - 80) * 16 + col];
                    val = w * __expf(w);                              // b
                }
            } else {                              // den columns, channel = col-16
                if (kap >= 80 && kap < 155) {
                    val = __expf(kw[(kap - 80) * 16 + (col - 16)]);   // a
                }
            }
            v[h] = val;
        }
        U2 p; p.h = __builtin_amdgcn_cvt_pkrtz(v[0], v[1]);
        sB[(dir * 32 + col) * DWPC + kd] = p.u;
    }
    __syncthreads();

    const int w  = tid >> 6;        // wave 0..3 -> 16-position sub-tile
    const int l  = tid & 63;
    const int g  = l >> 4;          // k-group
    const int pr = l & 15;          // A-row (position) / B-col (channel) / D-col (channel)
    const int b  = (int)blockIdx.y;
    const int p0 = (int)blockIdx.x * 64 + w * 16;
    if (p0 >= HWD) return;          // tail-block waves (after syncthreads; wave-uniform)

    // ---- B fragments -> registers (read once; 2-way bank aliasing = free) ----
    f16x8 bf[2][5][2];
    #pragma unroll
    for (int dir = 0; dir < 2; ++dir)
        #pragma unroll
        for (int t = 0; t < 5; ++t)
            #pragma unroll
            for (int f = 0; f < 2; ++f) {
                const unsigned* bp = &sB[(dir * 32 + f * 16 + pr) * DWPC + t * 16 + g * 4];
                bf[dir][t][f] = *(const f16x8*)bp;
            }

    // ---- main loop: build A fragments in-register, 4 MFMA per K-step ----
    const float* xb = x + (size_t)b * PATCHD * HWD + p0 + pr;
    f32x4 acc[2][2];
    #pragma unroll
    for (int dir = 0; dir < 2; ++dir)
        #pragma unroll
        for (int f = 0; f < 2; ++f)
            acc[dir][f] = (f32x4){0.f, 0.f, 0.f, 0.f};

    #pragma unroll
    for (int t = 0; t < 5; ++t) {
        UA A1, A2;
        #pragma unroll
        for (int jp = 0; jp < 4; ++jp) {
            float f1[2], f2[2];
            #pragma unroll
            for (int h = 0; h < 2; ++h) {
                const int kap = 32 * t + 8 * g + 2 * jp + h;
                float u1 = 0.f, u2 = 0.f;
                if (kap < 75) {
                    const float xv = xb[kap * HWD];
                    const float E  = __expf(xv);
                    const float R  = __builtin_amdgcn_rcpf(E);
                    u1 = E * xv;            // Ex
                    u2 = -(R * xv);         // -Rx
                } else if (kap >= 80 && kap < 155) {
                    const float xv = xb[(kap - 80) * HWD];
                    const float E  = __expf(xv);
                    u1 = E;
                    u2 = __builtin_amdgcn_rcpf(E);   // R
                }
                f1[h] = u1; f2[h] = u2;
            }
            U2 q1; q1.h = __builtin_amdgcn_cvt_pkrtz(f1[0], f1[1]);
            U2 q2; q2.h = __builtin_amdgcn_cvt_pkrtz(f2[0], f2[1]);
            A1.u[jp] = q1.u;
            A2.u[jp] = q2.u;
        }
        acc[0][0] = __builtin_amdgcn_mfma_f32_16x16x32_f16(A1.v, bf[0][t][0], acc[0][0], 0, 0, 0);
        acc[0][1] = __builtin_amdgcn_mfma_f32_16x16x32_f16(A1.v, bf[0][t][1], acc[0][1], 0, 0, 0);
        acc[1][0] = __builtin_amdgcn_mfma_f32_16x16x32_f16(A2.v, bf[1][t][0], acc[1][0], 0, 0, 0);
        acc[1][1] = __builtin_amdgcn_mfma_f32_16x16x32_f16(A2.v, bf[1][t][1], acc[1][1], 0, 0, 0);
    }

    // ---- epilogue: y = num1/den1 + num2/den2 + bias ----
    // D layout: col(channel) = l&15 = pr, row(position) = g*4 + r
    const float bs = bias[pr];
    float* ob = out + ((size_t)b * 16 + pr) * HWD + p0 + g * 4;
    #pragma unroll
    for (int r = 0; r < 4; ++r) {
        const float y = acc[0][0][r] * __builtin_amdgcn_rcpf(acc[0][1][r])
                      + acc[1][0][r] * __builtin_amdgcn_rcpf(acc[1][1][r])
                      + bs;
        ob[r] = y;
    }
}

extern "C" void kernel_launch(void* const* d_in, const int* in_sizes, int n_in,
                              void* d_out, int out_size, void* d_ws, size_t ws_size,
                              hipStream_t stream)
{
    const float* x    = (const float*)d_in[0];
    const float* k1   = (const float*)d_in[1];
    const float* k2   = (const float*)d_in[2];
    const float* bias = (const float*)d_in[3];
    float* out = (float*)d_out;

    dim3 grid((HWD + 63) / 64, 2);   // 757 x 2 batches; tail block has exactly one full 16-pos wave
    smorph_mfma<<<grid, 256, 0, stream>>>(x, k1, k2, bias, out);
}

// Round 5
// 23.970 us; speedup vs baseline: 2.0278x; 2.0278x over previous
//
#include <hip/hip_runtime.h>

#define HWD    48400          // 220*220
#define PATCHD 75
#define NPOS   96800          // 2 * HWD

typedef __attribute__((ext_vector_type(8))) _Float16 f16x8;
typedef __attribute__((ext_vector_type(2))) __fp16   h16x2;   // cvt_pkrtz return type
typedef __attribute__((ext_vector_type(4))) float    f32x4;

union U2 { h16x2 h; unsigned u; };
union UF { unsigned u[4]; f16x8 v; };

// GEMM formulation (per direction):
//   D[ch][pos] : num = T_num (16 x 192) x F (192 x 16), den = T_a (16 x 96) x F_E (96 x 16)
//   K halves padded to 96 so k and k+96 live in the SAME lane (s and s+3, same g):
//     kappa in [0,96):   F = E*x (dir1) / -R*x (dir2);  T_num = a = exp(w)
//     kappa in [96,192): F = E (dir1) / R (dir2);       T_num = b = w*exp(w)
//   den reuses T_num(s=0..2) as A and F(s=3..5) as B -> zero extra registers.
// A-frag: lane l -> row(ch)=l&15,  k = 32s + 8*(l>>4) + j
// B-frag: lane l -> col(pos)=l&15, k = 32s + 8*(l>>4) + j
// D:      lane l -> col(pos)=l&15, row(ch) = 4*(l>>4) + r

__global__ __launch_bounds__(256)
void smorph_mfma2(const float* __restrict__ x,
                  const float* __restrict__ k1,
                  const float* __restrict__ k2,
                  const float* __restrict__ bias,
                  float* __restrict__ out)
{
    const int tid = (int)threadIdx.x;
    const int l   = tid & 63;
    const int w   = tid >> 6;
    const int g   = l >> 4;         // k-subgroup 0..3
    const int c   = l & 15;         // channel lane (A) / position lane (B,D)
    const int p0  = (int)blockIdx.x * 64 + w * 16;
    if (p0 >= NPOS) return;         // no barriers anywhere -> safe early exit
    const int b   = (p0 >= HWD) ? 1 : 0;   // HWD % 16 == 0: waves never straddle batches
    const int hw0 = p0 - b * HWD;

    // ---- A-operand: weight-table fragments (built from L1-resident k1/k2) ----
    f16x8 ta[2][6];                 // [dir][s]; s=0..2: a=exp(w); s=3..5: b=w*exp(w)
    #pragma unroll
    for (int dir = 0; dir < 2; ++dir) {
        const float* kw = dir ? k2 : k1;
        #pragma unroll
        for (int s = 0; s < 3; ++s) {
            UF fa, fbv;
            #pragma unroll
            for (int jp = 0; jp < 4; ++jp) {
                float av[2], bv[2];
                #pragma unroll
                for (int h = 0; h < 2; ++h) {
                    const int k = 32 * s + 8 * g + 2 * jp + h;
                    float a = 0.f, bb = 0.f;
                    if (k < PATCHD) {
                        const float wv = kw[k * 16 + c];
                        const float e  = __expf(wv);
                        a  = e;
                        bb = wv * e;
                    }
                    av[h] = a; bv[h] = bb;
                }
                U2 pa; pa.h = __builtin_amdgcn_cvt_pkrtz(av[0], av[1]); fa.u[jp]  = pa.u;
                U2 pb; pb.h = __builtin_amdgcn_cvt_pkrtz(bv[0], bv[1]); fbv.u[jp] = pb.u;
            }
            ta[dir][s]     = fa.v;
            ta[dir][s + 3] = fbv.v;
        }
    }

    // ---- B-operand: feature fragments (x loaded ONCE, E reused for all four roles) ----
    const float* xb = x + (size_t)b * PATCHD * HWD + hw0 + c;
    f16x8 fb1[6], fb2[6];           // dir1: [Ex | E], dir2: [-Rx | R]
    #pragma unroll
    for (int s = 0; s < 3; ++s) {
        UF uEx, uE, uRx, uR;
        #pragma unroll
        for (int jp = 0; jp < 4; ++jp) {
            float ex[2], e_[2], rx[2], r_[2];
            #pragma unroll
            for (int h = 0; h < 2; ++h) {
                const int k = 32 * s + 8 * g + 2 * jp + h;
                float vE = 0.f, vEx = 0.f, vR = 0.f, vRx = 0.f;
                if (k < PATCHD) {
                    const float xv = xb[(size_t)k * HWD];
                    const float E  = __expf(xv);
                    const float R  = __builtin_amdgcn_rcpf(E);
                    vE  = E;
                    vEx = E * xv;
                    vR  = R;
                    vRx = -(R * xv);
                }
                ex[h] = vEx; e_[h] = vE; rx[h] = vRx; r_[h] = vR;
            }
            U2 q;
            q.h = __builtin_amdgcn_cvt_pkrtz(ex[0], ex[1]); uEx.u[jp] = q.u;
            q.h = __builtin_amdgcn_cvt_pkrtz(e_[0], e_[1]); uE.u[jp]  = q.u;
            q.h = __builtin_amdgcn_cvt_pkrtz(rx[0], rx[1]); uRx.u[jp] = q.u;
            q.h = __builtin_amdgcn_cvt_pkrtz(r_[0], r_[1]); uR.u[jp]  = q.u;
        }
        fb1[s] = uEx.v; fb1[s + 3] = uE.v;
        fb2[s] = uRx.v; fb2[s + 3] = uR.v;
    }

    // ---- 18 MFMAs, all operands in registers ----
    f32x4 aN1 = {0.f,0.f,0.f,0.f}, aD1 = {0.f,0.f,0.f,0.f};
    f32x4 aN2 = {0.f,0.f,0.f,0.f}, aD2 = {0.f,0.f,0.f,0.f};
    #pragma unroll
    for (int s = 0; s < 6; ++s) {
        aN1 = __builtin_amdgcn_mfma_f32_16x16x32_f16(ta[0][s], fb1[s], aN1, 0, 0, 0);
        aN2 = __builtin_amdgcn_mfma_f32_16x16x32_f16(ta[1][s], fb2[s], aN2, 0, 0, 0);
    }
    #pragma unroll
    for (int s = 0; s < 3; ++s) {
        aD1 = __builtin_amdgcn_mfma_f32_16x16x32_f16(ta[0][s], fb1[s + 3], aD1, 0, 0, 0);
        aD2 = __builtin_amdgcn_mfma_f32_16x16x32_f16(ta[1][s], fb2[s + 3], aD2, 0, 0, 0);
    }

    // ---- epilogue: y = num1/den1 + num2/den2 + bias; coalesced 64B stores ----
    float* ob = out + ((size_t)(b * 16 + g * 4)) * HWD + hw0 + c;
    #pragma unroll
    for (int r = 0; r < 4; ++r) {
        const float y = aN1[r] * __builtin_amdgcn_rcpf(aD1[r])
                      + aN2[r] * __builtin_amdgcn_rcpf(aD2[r])
                      + bias[g * 4 + r];
        ob[(size_t)r * HWD] = y;
    }
}

extern "C" void kernel_launch(void* const* d_in, const int* in_sizes, int n_in,
                              void* d_out, int out_size, void* d_ws, size_t ws_size,
                              hipStream_t stream)
{
    const float* x    = (const float*)d_in[0];
    const float* k1   = (const float*)d_in[1];
    const float* k2   = (const float*)d_in[2];
    const float* bias = (const float*)d_in[3];
    float* out = (float*)d_out;

    smorph_mfma2<<<(NPOS + 63) / 64, 256, 0, stream>>>(x, k1, k2, bias, out);
}

// Round 6
// 19.133 us; speedup vs baseline: 2.5404x; 1.2528x over previous
//
#include <hip/hip_runtime.h>

#define HWD    48400          // 220*220
#define PATCHD 75
#define NPOS   96800          // 2 * HWD
#define KPAD   96             // padded K per half (3 MFMA K-steps of 32)

typedef __attribute__((ext_vector_type(8))) _Float16 f16x8;
typedef __attribute__((ext_vector_type(2))) __fp16   h16x2;   // cvt_pkrtz return type
typedef __attribute__((ext_vector_type(4))) float    f32x4;

union U2 { h16x2 h; unsigned u; };
union UF { unsigned u[4]; f16x8 v; };

// ---------------------------------------------------------------------------
// Table build: tbl[role][c][k], f16, k-major, zero-padded to KPAD.
//   role 0 = exp(k1), 1 = k1*exp(k1), 2 = exp(k2), 3 = k2*exp(k2)
// 4 * 16 * 96 * 2B = 12 KB in d_ws.
// ---------------------------------------------------------------------------
__global__ void smorph_build_tables(const float* __restrict__ k1,
                                    const float* __restrict__ k2,
                                    _Float16* __restrict__ tbl)
{
    int i = (int)blockIdx.x * 256 + (int)threadIdx.x;   // (dir, c, k)
    if (i >= 2 * 16 * KPAD) return;
    int dir = i / (16 * KPAD);
    int r   = i - dir * (16 * KPAD);
    int c   = r / KPAD;
    int k   = r - c * KPAD;
    const float* kw = dir ? k2 : k1;
    float a = 0.f, b = 0.f;
    if (k < PATCHD) {
        float w = kw[k * 16 + c];
        float e = __expf(w);
        a = e;
        b = w * e;
    }
    tbl[(dir * 2 + 0) * (16 * KPAD) + c * KPAD + k] = (_Float16)a;
    tbl[(dir * 2 + 1) * (16 * KPAD) + c * KPAD + k] = (_Float16)b;
}

// ---------------------------------------------------------------------------
// Main: per wave, 16 positions x 16 channels, two directions.
//   num = [a|b] (16x192) x [Ex|E] (192x16), den = a (16x96) x E (96x16)
// A-frag lane l: row(ch)=l&15,  k = 32s + 8*(l>>4) + j  -> 4 dword table loads
// B-frag lane l: col(pos)=l&15, k same                  -> built from x in-reg
// D lane l: col(pos)=l&15, row(ch)=4*(l>>4)+r
// Rolled s-loop keeps live set ~100 VGPRs -> 4 waves/SIMD.
// ---------------------------------------------------------------------------
__global__ __launch_bounds__(256, 4)
void smorph_mfma3(const float* __restrict__ x,
                  const _Float16* __restrict__ tbl,
                  const float* __restrict__ bias,
                  float* __restrict__ out)
{
    const int tid = (int)threadIdx.x;
    const int l   = tid & 63;
    const int w   = tid >> 6;
    const int g   = l >> 4;         // k-subgroup 0..3
    const int c   = l & 15;         // channel lane (A) / position lane (B,D)
    const int p0  = (int)blockIdx.x * 64 + w * 16;
    if (p0 >= NPOS) return;         // no barriers anywhere -> safe
    const int b   = (p0 >= HWD) ? 1 : 0;   // HWD % 16 == 0: no straddle
    const int hw0 = p0 - b * HWD;

    const _Float16* tA1 = tbl + 0 * (16 * KPAD) + c * KPAD;
    const _Float16* tB1 = tbl + 1 * (16 * KPAD) + c * KPAD;
    const _Float16* tA2 = tbl + 2 * (16 * KPAD) + c * KPAD;
    const _Float16* tB2 = tbl + 3 * (16 * KPAD) + c * KPAD;

    const float* xb = x + (size_t)b * PATCHD * HWD + hw0 + c;

    f32x4 aN1 = {0.f,0.f,0.f,0.f}, aD1 = {0.f,0.f,0.f,0.f};
    f32x4 aN2 = {0.f,0.f,0.f,0.f}, aD2 = {0.f,0.f,0.f,0.f};

    #pragma unroll 1
    for (int s = 0; s < 3; ++s) {
        const int kbase = 32 * s + 8 * g;
        const float* xs = xb + (size_t)kbase * HWD;

        // 8 guarded x loads (OOB lanes: value irrelevant, table side is 0)
        float xv[8], E[8], R[8];
        #pragma unroll
        for (int j = 0; j < 8; ++j) {
            const int k = kbase + j;
            xv[j] = (k < PATCHD) ? xs[(size_t)j * HWD] : 0.f;
        }
        #pragma unroll
        for (int j = 0; j < 8; ++j) {
            E[j] = __expf(xv[j]);       // exp(x)
            R[j] = __expf(-xv[j]);      // exp(-x), independent of E
        }

        // feature fragments
        UF fEx, fE, fRx, fR;
        #pragma unroll
        for (int jp = 0; jp < 4; ++jp) {
            U2 q;
            q.h = __builtin_amdgcn_cvt_pkrtz(E[2*jp] * xv[2*jp], E[2*jp+1] * xv[2*jp+1]);
            fEx.u[jp] = q.u;
            q.h = __builtin_amdgcn_cvt_pkrtz(E[2*jp], E[2*jp+1]);
            fE.u[jp]  = q.u;
            q.h = __builtin_amdgcn_cvt_pkrtz(R[2*jp] * -xv[2*jp], R[2*jp+1] * -xv[2*jp+1]);
            fRx.u[jp] = q.u;
            q.h = __builtin_amdgcn_cvt_pkrtz(R[2*jp], R[2*jp+1]);
            fR.u[jp]  = q.u;
        }

        // weight fragments: 16 aligned dword loads, L1-resident 12KB table
        UF a1f, b1f, a2f, b2f;
        #pragma unroll
        for (int jp = 0; jp < 4; ++jp) {
            a1f.u[jp] = *(const unsigned*)(tA1 + kbase + 2 * jp);
            b1f.u[jp] = *(const unsigned*)(tB1 + kbase + 2 * jp);
            a2f.u[jp] = *(const unsigned*)(tA2 + kbase + 2 * jp);
            b2f.u[jp] = *(const unsigned*)(tB2 + kbase + 2 * jp);
        }

        aN1 = __builtin_amdgcn_mfma_f32_16x16x32_f16(a1f.v, fEx.v, aN1, 0, 0, 0);
        aN1 = __builtin_amdgcn_mfma_f32_16x16x32_f16(b1f.v, fE.v,  aN1, 0, 0, 0);
        aD1 = __builtin_amdgcn_mfma_f32_16x16x32_f16(a1f.v, fE.v,  aD1, 0, 0, 0);
        aN2 = __builtin_amdgcn_mfma_f32_16x16x32_f16(a2f.v, fRx.v, aN2, 0, 0, 0);
        aN2 = __builtin_amdgcn_mfma_f32_16x16x32_f16(b2f.v, fR.v,  aN2, 0, 0, 0);
        aD2 = __builtin_amdgcn_mfma_f32_16x16x32_f16(a2f.v, fR.v,  aD2, 0, 0, 0);
    }

    // epilogue: y = num1/den1 + num2/den2 + bias; coalesced 64B-segment stores
    float* ob = out + ((size_t)(b * 16 + 4 * g)) * HWD + hw0 + c;
    #pragma unroll
    for (int r = 0; r < 4; ++r) {
        const float y = aN1[r] * __builtin_amdgcn_rcpf(aD1[r])
                      + aN2[r] * __builtin_amdgcn_rcpf(aD2[r])
                      + bias[4 * g + r];
        ob[(size_t)r * HWD] = y;
    }
}

extern "C" void kernel_launch(void* const* d_in, const int* in_sizes, int n_in,
                              void* d_out, int out_size, void* d_ws, size_t ws_size,
                              hipStream_t stream)
{
    const float* x    = (const float*)d_in[0];
    const float* k1   = (const float*)d_in[1];
    const float* k2   = (const float*)d_in[2];
    const float* bias = (const float*)d_in[3];
    float* out = (float*)d_out;
    _Float16* tbl = (_Float16*)d_ws;     // 12 KB

    smorph_build_tables<<<(2 * 16 * KPAD + 255) / 256, 256, 0, stream>>>(k1, k2, tbl);
    smorph_mfma3<<<(NPOS + 63) / 64, 256, 0, stream>>>(x, tbl, bias, out);
}